// Round 1
// baseline (105.018 us; speedup 1.0000x reference)
//
#include <hip/hip_runtime.h>
#include <stdint.h>

#define TILE_LEN 16
#define KMAX 64
#define IMGW 512
#define IMGH 512
#define TXN (IMGW / TILE_LEN)   // 32
#define TYN (IMGH / TILE_LEN)   // 32
#define JCH 2048                // j-slice length for rank kernel
#define NSLICE 8

// ---------------------------------------------------------------------------
// Kernel 1: partial rank counts. key_i = (float_bits(depth_i) << 32) | i
// rank_i = #{ j : key_j < key_i }  -> stable argsort permutation.
// Grid: (N/256, NSLICE). Each block counts its i's against one j-slice.
// ---------------------------------------------------------------------------
__global__ __launch_bounds__(256) void rank_partial(
    const float* __restrict__ depth, int* __restrict__ rank, int N)
{
    __shared__ float sd[JCH];
    const int i = blockIdx.x * 256 + threadIdx.x;
    const int jbase = blockIdx.y * JCH;
    const int jcnt = min(JCH, N - jbase);

    for (int k = threadIdx.x; k < jcnt; k += 256)
        sd[k] = depth[jbase + k];
    __syncthreads();

    if (i >= N) return;

    const uint32_t bi = __float_as_uint(depth[i]);
    const uint64_t ki = ((uint64_t)bi << 32) | (uint32_t)i;

    int cnt = 0;
#pragma unroll 8
    for (int j = 0; j < jcnt; ++j) {
        uint64_t kj = ((uint64_t)__float_as_uint(sd[j]) << 32) | (uint32_t)(jbase + j);
        cnt += (kj < ki) ? 1 : 0;
    }
    atomicAdd(&rank[i], cnt);
}

// ---------------------------------------------------------------------------
// Kernel 2: scatter gaussians into depth-sorted SoA.
// sA = (px, py, radius, opacity); sB = (a, b, c, det); sC = (r, g, b, 0)
// Radius chain uses _rn intrinsics to forbid fma contraction (selection-
// critical: feeds the exact bbox-overlap compare).
// ---------------------------------------------------------------------------
__global__ __launch_bounds__(256) void scatter_sorted(
    const float* __restrict__ pos2d, const float* __restrict__ cov2d,
    const float* __restrict__ opac,  const float* __restrict__ color,
    const int* __restrict__ rank,
    float4* __restrict__ sA, float4* __restrict__ sB, float4* __restrict__ sC,
    int N)
{
    const int i = blockIdx.x * 256 + threadIdx.x;
    if (i >= N) return;

    const float a = cov2d[4 * i + 0];
    const float b = cov2d[4 * i + 1];
    const float c = cov2d[4 * i + 3];

    const float trace = __fadd_rn(a, c);
    const float det   = __fsub_rn(__fmul_rn(a, c), __fmul_rn(b, b));
    const float tt    = __fmul_rn(trace, trace);
    float arg         = __fsub_rn(tt, __fmul_rn(4.0f, det));
    arg = fmaxf(arg, 0.0f);
    const float t1 = __fmul_rn(0.5f, trace);
    const float t2 = __fmul_rn(0.5f, sqrtf(arg));
    const float lam = fmaxf(__fsub_rn(t1, t2), __fadd_rn(t1, t2));
    const float radius = __fmul_rn(3.0f, sqrtf(lam));

    const int r = rank[i];
    sA[r] = make_float4(pos2d[2 * i], pos2d[2 * i + 1], radius, opac[i]);
    sB[r] = make_float4(a, b, c, det);
    sC[r] = make_float4(color[3 * i], color[3 * i + 1], color[3 * i + 2], 0.0f);
}

// ---------------------------------------------------------------------------
// Kernel 3: per-tile render. One block per tile, 256 threads = 256 pixels.
// Phase 1: scan sorted gaussians in chunks of 256, ballot-compact first
//          KMAX bbox-overlapping ones (depth order preserved).
// Phase 2: fetch their params to LDS, per-pixel front-to-back blend.
// ---------------------------------------------------------------------------
__global__ __launch_bounds__(256) void render_tiles(
    const float4* __restrict__ sA, const float4* __restrict__ sB,
    const float4* __restrict__ sC, float* __restrict__ out, int N)
{
    __shared__ int    s_list[KMAX];
    __shared__ int    s_wcnt[4];
    __shared__ float4 pA[KMAX], pB[KMAX], pC[KMAX];

    const int tile = blockIdx.x;
    const int tx = tile / TYN;
    const int ty = tile % TYN;
    const float Lf = (float)(tx * TILE_LEN);
    const float Tf = (float)(ty * TILE_LEN);
    const int t = threadIdx.x;
    const int lane = t & 63;
    const int w = t >> 6;

    // ---- Phase 1: ordered compaction of first KMAX overlapping gaussians
    int count = 0;  // block-uniform
    for (int base = 0; base < N; base += 256) {
        const int g = base + t;
        bool ov = false;
        if (g < N) {
            const float4 A = sA[g];
            const float xp = __fadd_rn(A.x, A.z);
            const float xm = __fsub_rn(A.x, A.z);
            const float yp = __fadd_rn(A.y, A.z);
            const float ym = __fsub_rn(A.y, A.z);
            ov = (xp > Lf) && (xm < Lf + (float)TILE_LEN) &&
                 (yp > Tf) && (ym < Tf + (float)TILE_LEN);
        }
        const unsigned long long m = __ballot(ov);
        if (lane == 0) s_wcnt[w] = __popcll(m);
        __syncthreads();
        const int c0 = s_wcnt[0], c1 = s_wcnt[1], c2 = s_wcnt[2], c3 = s_wcnt[3];
        int off = count;
        if (w > 0) off += c0;
        if (w > 1) off += c1;
        if (w > 2) off += c2;
        const int pos = off + __popcll(m & ((1ull << lane) - 1ull));
        if (ov && pos < KMAX) s_list[pos] = g;
        count = min(KMAX, count + c0 + c1 + c2 + c3);
        __syncthreads();
        if (count >= KMAX) break;
    }

    // ---- fetch selected gaussian params into LDS
    if (t < count) {
        const int g = s_list[t];
        pA[t] = sA[g];
        pB[t] = sB[g];
        pC[t] = sC[g];
    }
    __syncthreads();

    // ---- Phase 2: per-pixel blend (pixel (i,j): x = left+i, y = top+j)
    const int j = t & 15;
    const int i = t >> 4;
    const float x = Lf + (float)i;
    const float y = Tf + (float)j;

    float Tacc = 1.0f, cr = 0.0f, cg = 0.0f, cb = 0.0f;
    for (int k = 0; k < count; ++k) {
        const float4 A = pA[k];
        const float4 B = pB[k];
        const float4 C = pC[k];
        const float dx = x - A.x;
        const float dy = y - A.y;
        const float quad = (B.z * dx * dx - 2.0f * B.y * dx * dy + B.x * dy * dy) / B.w;
        const float prob = expf(-0.5f * quad);
        const float alpha = fminf(fmaxf(A.w * prob, 0.01f), 0.99f);
        const float wgt = alpha * Tacc;
        cr = fmaf(wgt, C.x, cr);
        cg = fmaf(wgt, C.y, cg);
        cb = fmaf(wgt, C.z, cb);
        Tacc *= (1.0f - alpha);
    }

    const int X = tx * TILE_LEN + i;
    const int Y = ty * TILE_LEN + j;
    float* o = out + ((size_t)X * IMGW + (size_t)Y) * 3;
    o[0] = cr;
    o[1] = cg;
    o[2] = cb;
}

// ---------------------------------------------------------------------------
extern "C" void kernel_launch(void* const* d_in, const int* in_sizes, int n_in,
                              void* d_out, int out_size, void* d_ws, size_t ws_size,
                              hipStream_t stream)
{
    const float* pos2d = (const float*)d_in[0];
    const float* cov2d = (const float*)d_in[1];
    const float* opac  = (const float*)d_in[2];
    const float* color = (const float*)d_in[3];
    const float* depth = (const float*)d_in[4];
    float* out = (float*)d_out;

    const int N = in_sizes[2];  // opacity count == N_GAUSS

    // workspace layout: ranks (N int, padded to 64KiB), then sA/sB/sC float4[N]
    int* ranks = (int*)d_ws;
    char* base = (char*)d_ws + 65536;
    float4* sA = (float4*)base;
    float4* sB = sA + N;
    float4* sC = sB + N;

    hipMemsetAsync(ranks, 0, (size_t)N * sizeof(int), stream);

    dim3 g1((N + 255) / 256, NSLICE);
    rank_partial<<<g1, 256, 0, stream>>>(depth, ranks, N);

    scatter_sorted<<<(N + 255) / 256, 256, 0, stream>>>(
        pos2d, cov2d, opac, color, ranks, sA, sB, sC, N);

    render_tiles<<<TXN * TYN, 256, 0, stream>>>(sA, sB, sC, out, N);
}